// Round 12
// baseline (1781.506 us; speedup 1.0000x reference)
//
#include <hip/hip_runtime.h>

// R12: occupancy doubling. R11 diagnosis: latency/barrier-bound at 2 waves/
// SIMD (24% occ), pinned by 128KB LDS W_hh0. Weights are L2-fit -> ALL
// weight matrices become fragment-records in d_ws (prep kernel, 6 mats);
// LDS = 18KB (h0/h1 dbuf + x tile). 512 blocks x 512 thr, 16 rows/block,
// __launch_bounds__(512,4) -> 2 blocks/CU, 4 waves/SIMD. Encoder 2 barriers/
// step (dbuf h0+h1). sigm/tanh IEEE divisions -> v_rcp_f32 (approx, ~1e-7).
// Frag formats + mappings identical to R11's proven path. FP32 output.

using s16x8 = __attribute__((ext_vector_type(8))) short;
using h16x8 = __attribute__((ext_vector_type(8))) _Float16;
using f32x4 = __attribute__((ext_vector_type(4))) float;

#define DEV static __device__ __forceinline__

DEV unsigned short f2h(float f) {
  _Float16 h = (_Float16)f;  // RNE
  return __builtin_bit_cast(unsigned short, h);
}
DEV float h2f(short h) {
  return (float)__builtin_bit_cast(_Float16, (unsigned short)h);
}
DEV float rcp_(float x) { return __builtin_amdgcn_rcpf(x); }
DEV float sigm(float v) { return rcp_(1.0f + __expf(-v)); }
DEV float tanh_(float v) {
  float e = __expf(-2.0f * fabsf(v));
  float r = (1.0f - e) * rcp_(1.0f + e);
  return v < 0.0f ? -r : r;
}
DEV f32x4 mf(s16x8 a, s16x8 b, f32x4 c) {
  return __builtin_amdgcn_mfma_f32_16x16x32_f16(
      __builtin_bit_cast(h16x8, a), __builtin_bit_cast(h16x8, b), c, 0, 0, 0);
}
DEV f32x4 splat4(float v) { f32x4 r = {v, v, v, v}; return r; }

// [16][128] fp16 buffer; 16 slots of 8 fp16 per row, XOR-swizzled.
DEV int swz(int row, int slot) { return row * 256 + (((slot ^ row) & 15) << 4); }
DEV s16x8 ldA(const char* buf, int ks, int lo, int hi) {
  return *(const s16x8*)(buf + swz(lo, ks * 4 + hi));
}
DEV void storeH(char* buf, int row, int col, unsigned short v) {
  int addr = row * 256 + ((((col >> 3) ^ row) & 15) << 4) + (col & 7) * 2;
  *(unsigned short*)(buf + addr) = v;
}
// LSTM pointwise: gates (i,f,g,o) -> update c, return fp16(h)
DEV unsigned short cellup(float gi, float gf, float gg, float go, float& c) {
  float i = sigm(gi), f = sigm(gf), g2 = tanh_(gg), o = sigm(go);
  c = f * c + i * g2;
  return f2h(o * tanh_(c));
}

// ---- d_ws layout (bytes) ----
// 6 mats x 128KB frag records: addr = m*131072 + ks*32768 + col*64 + hi*16
//   m: 0=eWih1 1=eWhh1 2=dWih1 3=dWhh1 4=eWhh0 5=dWhh0
// WX (eWih0 K=16 zero-padded to 32): @786432, addr = col*64 + hi*16 (32KB)
#define WS_WX 786432

__global__ void prep_kernel(
    const float* __restrict__ eWih0,
    const float* __restrict__ eWih1, const float* __restrict__ eWhh1,
    const float* __restrict__ dWih1, const float* __restrict__ dWhh1,
    const float* __restrict__ eWhh0, const float* __restrict__ dWhh0,
    char* __restrict__ ws) {
  int idx = blockIdx.x * 256 + threadIdx.x;
  if (idx < 49152) {  // 6 mats x 8192 fragment records
    int m = idx >> 13, r = idx & 8191;
    int col = r >> 4, ks = (r >> 2) & 3, hi = r & 3;
    const float* W;
    switch (m) {
      case 0: W = eWih1; break;
      case 1: W = eWhh1; break;
      case 2: W = dWih1; break;
      case 3: W = dWhh1; break;
      case 4: W = eWhh0; break;
      default: W = dWhh0; break;
    }
    const float* p = W + col * 128 + ks * 32 + hi * 8;
    s16x8 v;
#pragma unroll
    for (int j = 0; j < 8; ++j) v[j] = (short)f2h(p[j]);
    *(s16x8*)(ws + m * 131072 + ks * 32768 + col * 64 + hi * 16) = v;
  } else if (idx < 51200) {  // x-projection frags (K=16 -> 32 zero-pad)
    int r3 = idx - 49152;
    int col = r3 >> 2, hi = r3 & 3;
    s16x8 v;
#pragma unroll
    for (int j = 0; j < 8; ++j) v[j] = 0;
    if (hi < 2) {
      const float* p = eWih0 + col * 16 + hi * 8;
#pragma unroll
      for (int j = 0; j < 8; ++j) v[j] = (short)f2h(p[j]);
    }
    *(s16x8*)(ws + WS_WX + col * 64 + hi * 16) = v;
  }
}

__global__ __launch_bounds__(512, 4) void fused_kernel(
    const float* __restrict__ x,
    const float* __restrict__ ebih0, const float* __restrict__ ebhh0,
    const float* __restrict__ ebih1, const float* __restrict__ ebhh1,
    const float* __restrict__ dWih0,
    const float* __restrict__ dbih0, const float* __restrict__ dbhh0,
    const float* __restrict__ dbih1, const float* __restrict__ dbhh1,
    const float* __restrict__ fcW, const float* __restrict__ fcb,
    const char* __restrict__ ws, float* __restrict__ out) {
  __shared__ __align__(16) char smem[18304];
  char* h0B  = smem;                       // 2 x 4096 double buffer
  char* h1B  = smem + 8192;                // 2 x 4096 double buffer
  char* xL   = smem + 16384;               // 16 rows * 80B (K pad to 32)
  float* inpL = (float*)(smem + 17664);    // 16x2 fp32 decoder feedback
  char* fcwL = smem + 17792;               // 2x128 fp16

  const int tid = threadIdx.x;
  const int w = tid >> 6, l = tid & 63, lo = l & 15, hi = l >> 4;
  const int row0 = blockIdx.x * 16;
  const int colb = w * 16;
  const int obase = (colb + lo) * 64 + hi * 16;  // frag offset within record blk

  {  // zero h0B, h1B, xL (contiguous 17664 B = 1104 int4)
    int4 z = make_int4(0, 0, 0, 0);
    int4* p = (int4*)smem;
    for (int i = tid; i < 1104; i += 512) p[i] = z;
  }

  float b0[4], b1[4];
  s16x8 wx0[4];
#pragma unroll
  for (int g = 0; g < 4; ++g) {
    int col = g * 128 + colb + lo;
    b0[g] = ebih0[col] + ebhh0[col];
    b1[g] = ebih1[col] + ebhh1[col];
    wx0[g] = *(const s16x8*)(ws + WS_WX + g * 8192 + obase);
  }
  float c0s[4], c1s[4];
#pragma unroll
  for (int r = 0; r < 4; ++r) { c0s[r] = 0.f; c1s[r] = 0.f; }

  const int xr = tid >> 4, xf = tid & 15;
  const float* xrow = x + (long long)(row0 + xr) * 1600 + xf;
  float xv = (tid < 256) ? xrow[0] : 0.f;
  int cur = 0;

  // ================= encoder (T=100) =================
  for (int t = 0; t < 100; ++t) {
    if (tid < 256) *(unsigned short*)(xL + xr * 80 + xf * 2) = f2h(xv);
    __syncthreads();  // B1: xL + prev h1 writes visible
    if (t < 99 && tid < 256) xv = xrow[(t + 1) * 16];  // prefetch

    char* h0r = h0B + cur * 4096;
    char* h0w = h0B + (cur ^ 1) * 4096;
    char* h1r = h1B + cur * 4096;
    char* h1w = h1B + (cur ^ 1) * 4096;

    // ---- layer 0: g = x@Wih0^T + h0@Whh0^T + b0 (W_hh0 frags: mat 4)
    f32x4 acc[4];
#pragma unroll
    for (int g = 0; g < 4; ++g) acc[g] = splat4(b0[g]);
    {
      s16x8 ax = *(const s16x8*)(xL + lo * 80 + hi * 16);
#pragma unroll
      for (int g = 0; g < 4; ++g) acc[g] = mf(ax, wx0[g], acc[g]);
    }
    int lf0 = 0;
    asm("" : "+s"(lf0));  // defeat LICM (no 64-reg hoist)
    const char* W0 = ws + 4 * 131072 + lf0;
#pragma unroll
    for (int ks = 0; ks < 4; ++ks) {
      s16x8 a0 = ldA(h0r, ks, lo, hi);
      const char* wk = W0 + ks * 32768 + obase;
#pragma unroll
      for (int g = 0; g < 4; ++g) {
        s16x8 bb = *(const s16x8*)(wk + g * 8192);
        acc[g] = mf(a0, bb, acc[g]);
      }
    }
    unsigned short hb[4];
#pragma unroll
    for (int r = 0; r < 4; ++r)
      hb[r] = cellup(acc[0][r], acc[1][r], acc[2][r], acc[3][r], c0s[r]);
#pragma unroll
    for (int r = 0; r < 4; ++r) storeH(h0w, hi * 4 + r, colb + lo, hb[r]);
    __syncthreads();  // B2: h0-new visible

    // ---- layer 1: g = h0new@Wih1^T + h1@Whh1^T + b1 (mats 0/1)
#pragma unroll
    for (int g = 0; g < 4; ++g) acc[g] = splat4(b1[g]);
    int lf1 = 0;
    asm("" : "+s"(lf1));
    const char* W1 = ws + lf1;
#pragma unroll
    for (int s = 0; s < 8; ++s) {
      const char* src = (s < 4) ? h0w : h1r;
      int ks = s & 3;
      const char* wk = W1 + (s < 4 ? 0 : 131072) + ks * 32768 + obase;
      s16x8 a0 = ldA(src, ks, lo, hi);
#pragma unroll
      for (int g = 0; g < 4; ++g) {
        s16x8 bb = *(const s16x8*)(wk + g * 8192);
        acc[g] = mf(a0, bb, acc[g]);
      }
    }
#pragma unroll
    for (int r = 0; r < 4; ++r)
      hb[r] = cellup(acc[0][r], acc[1][r], acc[2][r], acc[3][r], c1s[r]);
#pragma unroll
    for (int r = 0; r < 4; ++r) storeH(h1w, hi * 4 + r, colb + lo, hb[r]);
    cur ^= 1;  // h1w visibility covered by next step's B1
  }

  // ================= restage for decoder =================
  float dwx[4][2];
#pragma unroll
  for (int g = 0; g < 4; ++g) {
    int col = g * 128 + colb + lo;
    b0[g] = dbih0[col] + dbhh0[col];
    b1[g] = dbih1[col] + dbhh1[col];
    dwx[g][0] = dWih0[col * 2 + 0];
    dwx[g][1] = dWih0[col * 2 + 1];
  }
  if (tid < 32) {  // dec_in = x[:, 99, :2] (fp32)
    int r = tid >> 1, o = tid & 1;
    inpL[r * 2 + o] = x[(long long)(row0 + r) * 1600 + 1584 + o];
  }
  if (tid < 256) {
    int o = tid >> 7, k = tid & 127;
    *(unsigned short*)(fcwL + o * 256 + k * 2) = f2h(fcW[o * 128 + k]);
  }
  float fb0 = fcb[0], fb1 = fcb[1];
  __syncthreads();  // decoder inputs + final h states visible

  // ================= decoder (TGT=60) =================
  for (int t = 0; t < 60; ++t) {
    char* h0r = h0B + cur * 4096;
    char* h0w = h0B + (cur ^ 1) * 4096;
    char* h1r = h1B + cur * 4096;
    char* h1w = h1B + (cur ^ 1) * 4096;

    // ---- layer 0: g = inp@dWih0^T (VALU, K=2) + h0@dWhh0^T (mat 5) + b0
    f32x4 acc[4];
#pragma unroll
    for (int r = 0; r < 4; ++r) {
      float2 ip = *(const float2*)(inpL + (hi * 4 + r) * 2);
#pragma unroll
      for (int g = 0; g < 4; ++g)
        acc[g][r] = b0[g] + ip.x * dwx[g][0] + ip.y * dwx[g][1];
    }
    int lf0 = 0;
    asm("" : "+s"(lf0));
    const char* W0 = ws + 5 * 131072 + lf0;
#pragma unroll
    for (int ks = 0; ks < 4; ++ks) {
      s16x8 a0 = ldA(h0r, ks, lo, hi);
      const char* wk = W0 + ks * 32768 + obase;
#pragma unroll
      for (int g = 0; g < 4; ++g) {
        s16x8 bb = *(const s16x8*)(wk + g * 8192);
        acc[g] = mf(a0, bb, acc[g]);
      }
    }
    unsigned short hb[4];
#pragma unroll
    for (int r = 0; r < 4; ++r)
      hb[r] = cellup(acc[0][r], acc[1][r], acc[2][r], acc[3][r], c0s[r]);
#pragma unroll
    for (int r = 0; r < 4; ++r) storeH(h0w, hi * 4 + r, colb + lo, hb[r]);
    __syncthreads();  // B2: h0-new visible

    // ---- layer 1 (mats 2/3)
#pragma unroll
    for (int g = 0; g < 4; ++g) acc[g] = splat4(b1[g]);
    int lf1 = 0;
    asm("" : "+s"(lf1));
    const char* W1 = ws + 2 * 131072 + lf1;
#pragma unroll
    for (int s = 0; s < 8; ++s) {
      const char* src = (s < 4) ? h0w : h1r;
      int ks = s & 3;
      const char* wk = W1 + (s < 4 ? 0 : 131072) + ks * 32768 + obase;
      s16x8 a0 = ldA(src, ks, lo, hi);
#pragma unroll
      for (int g = 0; g < 4; ++g) {
        s16x8 bb = *(const s16x8*)(wk + g * 8192);
        acc[g] = mf(a0, bb, acc[g]);
      }
    }
#pragma unroll
    for (int r = 0; r < 4; ++r)
      hb[r] = cellup(acc[0][r], acc[1][r], acc[2][r], acc[3][r], c1s[r]);
#pragma unroll
    for (int r = 0; r < 4; ++r) storeH(h1w, hi * 4 + r, colb + lo, hb[r]);
    __syncthreads();  // B3: h1-new visible for FC

    // ---- FC head + feedback (wave 0: lane -> (row=lo, o, kh))
    if (w == 0) {
      int o = hi & 1, kh = hi >> 1;
      float sum = 0.f;
#pragma unroll
      for (int cc = 0; cc < 8; ++cc) {
        s16x8 hv = *(const s16x8*)(h1w + swz(lo, kh * 8 + cc));
        s16x8 wv = *(const s16x8*)(fcwL + o * 256 + (kh * 8 + cc) * 16);
#pragma unroll
        for (int j = 0; j < 8; ++j) sum += h2f(hv[j]) * h2f(wv[j]);
      }
      sum += __shfl_xor(sum, 32, 64);
      if (l < 32) {
        float ov = sum + (o ? fb1 : fb0);
        inpL[lo * 2 + o] = ov;  // fp32 feedback, matches reference carry
        out[((long long)(row0 + lo) * 60 + t) * 2 + o] = ov;
      }
    }
    __syncthreads();  // B1(end): inpL visible for next step's layer 0
    cur ^= 1;
  }
}

extern "C" void kernel_launch(void* const* d_in, const int* in_sizes, int n_in,
                              void* d_out, int out_size, void* d_ws, size_t ws_size,
                              hipStream_t stream) {
  (void)in_sizes; (void)n_in; (void)out_size; (void)ws_size;
  const float* x      = (const float*)d_in[0];
  // d_in[1] = target_len (60), hardcoded
  const float* eWih0  = (const float*)d_in[2];
  const float* eWhh0  = (const float*)d_in[3];
  const float* ebih0  = (const float*)d_in[4];
  const float* ebhh0  = (const float*)d_in[5];
  const float* eWih1  = (const float*)d_in[6];
  const float* eWhh1  = (const float*)d_in[7];
  const float* ebih1  = (const float*)d_in[8];
  const float* ebhh1  = (const float*)d_in[9];
  const float* dWih0  = (const float*)d_in[10];
  const float* dWhh0  = (const float*)d_in[11];
  const float* dbih0  = (const float*)d_in[12];
  const float* dbhh0  = (const float*)d_in[13];
  const float* dWih1  = (const float*)d_in[14];
  const float* dWhh1  = (const float*)d_in[15];
  const float* dbih1  = (const float*)d_in[16];
  const float* dbhh1  = (const float*)d_in[17];
  const float* fcW    = (const float*)d_in[18];
  const float* fcb    = (const float*)d_in[19];
  float* out          = (float*)d_out;
  char* ws            = (char*)d_ws;

  prep_kernel<<<200, 256, 0, stream>>>(eWih0, eWih1, eWhh1, dWih1, dWhh1,
                                       eWhh0, dWhh0, ws);

  fused_kernel<<<512, 512, 0, stream>>>(
      x, ebih0, ebhh0, ebih1, ebhh1, dWih0, dbih0, dbhh0, dbih1, dbhh1,
      fcW, fcb, ws, out);
}